// Round 14
// baseline (2248.902 us; speedup 1.0000x reference)
//
#include <hip/hip_runtime.h>

#define N_ROWS 8192
#define DIM_D  1024
#define DIM_H  2048
#define DIM_O  1024
#define NEXP   8
#define NACT   5
#define MT128  336   // max 128-row tiles (8 * 42)

typedef _Float16 f16x8 __attribute__((ext_vector_type(8)));
typedef _Float16 f16x4 __attribute__((ext_vector_type(4)));
typedef float    f32x4 __attribute__((ext_vector_type(4)));

__device__ __forceinline__ void gload_lds16(const void* g, void* l) {
  __builtin_amdgcn_global_load_lds(
      (const __attribute__((address_space(1))) void*)g,
      (__attribute__((address_space(3))) void*)l, 16, 0, 0);
}

// ---------------- x: f32 -> f16 ----------------
__global__ void convert_x_kernel(const float* __restrict__ in,
                                 _Float16* __restrict__ out, int n) {
  int i = (blockIdx.x * 256 + threadIdx.x) * 8;
  if (i >= n) return;
  const float4 a = *(const float4*)(in + i);
  const float4 b = *(const float4*)(in + i + 4);
  f16x8 v;
  v[0] = (_Float16)a.x; v[1] = (_Float16)a.y; v[2] = (_Float16)a.z; v[3] = (_Float16)a.w;
  v[4] = (_Float16)b.x; v[5] = (_Float16)b.y; v[6] = (_Float16)b.z; v[7] = (_Float16)b.w;
  *(f16x8*)(out + i) = v;
}

// ---------------- zero helpers ----------------
__global__ void zero_f32_kernel(float* __restrict__ p, int n4) {
  int i = blockIdx.x * 256 + threadIdx.x;
  if (i < n4) ((float4*)p)[i] = make_float4(0.f, 0.f, 0.f, 0.f);
}
__global__ void zero_counts_kernel(int* __restrict__ cnt) {
  if (threadIdx.x < NEXP) cnt[threadIdx.x] = 0;
}

// ------- W [R][C] f32 -> Wt [C][R] f16 (batched over z), vectorized writes ---
// out[(c0+cc)*R + r0+rr] = tile[rr][cc]; one pass: lane -> cc = t>>3,
// rr = (t&7)*4..+3, 8B f16x4 store (R % 8 == 0 so alignment holds).
__global__ void transpose_to_f16(const float* __restrict__ in,
                                 _Float16* __restrict__ out, int R, int C) {
  in  += (size_t)blockIdx.z * R * C;
  out += (size_t)blockIdx.z * R * C;
  __shared__ float tile[32][33];
  const int tx = threadIdx.x & 31, ty = threadIdx.x >> 5;  // ty: 0..7
  const int c0 = blockIdx.x * 32, r0 = blockIdx.y * 32;
#pragma unroll
  for (int j = 0; j < 32; j += 8)
    tile[ty + j][tx] = in[(size_t)(r0 + ty + j) * C + c0 + tx];
  __syncthreads();
  const int cc = threadIdx.x >> 3;        // 0..31
  const int r4 = (threadIdx.x & 7) * 4;   // 0..28
  f16x4 v;
#pragma unroll
  for (int i = 0; i < 4; ++i) v[i] = (_Float16)tile[r4 + i][cc];
  *(f16x4*)(out + (size_t)(c0 + cc) * R + r0 + r4) = v;
}

// ---------------- gate: softmax(score/e), top-5, renorm ----------------
__global__ void gate_kernel(const float* __restrict__ x, const float* __restrict__ gW,
                            const float* __restrict__ gb, float* __restrict__ wout) {
  const int lane = threadIdx.x & 63;
  const int row  = blockIdx.x * 4 + (threadIdx.x >> 6);
  float acc[8] = {0.f,0.f,0.f,0.f,0.f,0.f,0.f,0.f};
  const float* xr = x + (size_t)row * DIM_D;
  for (int d = lane; d < DIM_D; d += 64) {
    float xv = xr[d];
    const float4* g4 = (const float4*)(gW + d * 8);
    float4 a = g4[0], b = g4[1];
    acc[0] += xv * a.x; acc[1] += xv * a.y; acc[2] += xv * a.z; acc[3] += xv * a.w;
    acc[4] += xv * b.x; acc[5] += xv * b.y; acc[6] += xv * b.z; acc[7] += xv * b.w;
  }
#pragma unroll
  for (int off = 32; off > 0; off >>= 1) {
#pragma unroll
    for (int e = 0; e < 8; ++e) acc[e] += __shfl_xor(acc[e], off);
  }
  const float invT = 0.36787944117144233f;  // 1/e
  float s[8], mx = -1e30f;
#pragma unroll
  for (int e = 0; e < 8; ++e) { s[e] = (acc[e] + gb[e]) * invT; mx = fmaxf(mx, s[e]); }
  float p[8], sum = 0.f;
#pragma unroll
  for (int e = 0; e < 8; ++e) { p[e] = expf(s[e] - mx); sum += p[e]; }
  float inv = 1.f / sum;
#pragma unroll
  for (int e = 0; e < 8; ++e) p[e] *= inv;
  unsigned keep = 0;
  for (int it = 0; it < NACT; ++it) {
    int best = 0; float bv = -1.f;
#pragma unroll
    for (int e = 0; e < 8; ++e)
      if (!(keep & (1u << e)) && p[e] > bv) { bv = p[e]; best = e; }
    keep |= 1u << best;
  }
  float ks = 0.f;
#pragma unroll
  for (int e = 0; e < 8; ++e) if (keep & (1u << e)) ks += p[e];
  const float winv = 1.f / (ks + 1e-8f);
  if (lane < 8)
    wout[(size_t)row * 8 + lane] = (keep & (1u << lane)) ? p[lane] * winv : 0.f;
}

// ---------------- count kept rows per expert ----------------
__global__ void count_kernel(const float* __restrict__ wg, int* __restrict__ cnt) {
  const int row = blockIdx.x * 256 + threadIdx.x;
  const int lane = threadIdx.x & 63;
#pragma unroll
  for (int e = 0; e < NEXP; ++e) {
    const bool keep = wg[(size_t)row * 8 + e] > 0.f;
    unsigned long long m = __ballot(keep);
    if (lane == 0 && m) atomicAdd(&cnt[e], __popcll(m));
  }
}

// ---------------- padded offsets (128-granular) + tile table + pad-fill ------
__global__ void offsets_kernel(const int* __restrict__ cnt, int* __restrict__ cursor,
                               int* __restrict__ offs, int* __restrict__ ntiles,
                               int2* __restrict__ ttab, int* __restrict__ rlist) {
  __shared__ int soffs[NEXP], scnt[NEXP];
  if (threadIdx.x == 0) {
    int off = 0, k = 0;
    for (int e = 0; e < NEXP; ++e) {
      offs[e] = off; soffs[e] = off; scnt[e] = cnt[e];
      cursor[e] = 0;
      const int nt = (cnt[e] + 127) >> 7;
      for (int t2 = 0; t2 < nt; ++t2) { ttab[k] = make_int2(e, off + t2 * 128); ++k; }
      off += nt << 7;
    }
    *ntiles = k;
  }
  __syncthreads();
#pragma unroll
  for (int e = 0; e < NEXP; ++e) {
    const int lo = soffs[e] + scnt[e];
    const int hi = soffs[e] + ((scnt[e] + 127) & ~127);
    for (int i = lo + (int)threadIdx.x; i < hi; i += 256) rlist[i] = 0;
  }
}

// ---------------- place rows into padded compact space ----------------
__global__ void place_kernel(const float* __restrict__ wg, const int* __restrict__ offs,
                             int* __restrict__ cursor, int* __restrict__ rlist,
                             int* __restrict__ pos) {
  const int row = blockIdx.x * 256 + threadIdx.x;
  const int lane = threadIdx.x & 63;
#pragma unroll
  for (int e = 0; e < NEXP; ++e) {
    const bool keep = wg[(size_t)row * 8 + e] > 0.f;
    unsigned long long m = __ballot(keep);
    if (m) {
      const int leader = __ffsll(m) - 1;
      const int pre = __popcll(m & ((1ull << lane) - 1ull));
      int base = 0;
      if (lane == leader) base = atomicAdd(&cursor[e], __popcll(m));
      base = __shfl(base, leader);
      if (keep) {
        const int idx = offs[e] + base + pre;
        rlist[idx] = row;
        pos[(size_t)row * 8 + e] = idx;
      }
    }
  }
}

// ---------------- combine: out[row] = sum_e w * y[pos[row][e]] ----------------
__global__ void combine_kernel(const float* __restrict__ wg, const int* __restrict__ pos,
                               const _Float16* __restrict__ y, float* __restrict__ out) {
  const int tid = blockIdx.x * 256 + threadIdx.x;
  const int row = tid >> 7, c8 = (tid & 127) * 8;
  float a[8] = {0.f,0.f,0.f,0.f,0.f,0.f,0.f,0.f};
#pragma unroll
  for (int e = 0; e < NEXP; ++e) {
    const float w = wg[(size_t)row * 8 + e];
    if (w > 0.f) {
      const int p = pos[(size_t)row * 8 + e];
      const f16x8 v = *(const f16x8*)(y + (size_t)p * DIM_O + c8);
#pragma unroll
      for (int j = 0; j < 8; ++j) a[j] += w * (float)v[j];
    }
  }
  float4* o4 = (float4*)(out + (size_t)row * DIM_O + c8);
  o4[0] = make_float4(a[0], a[1], a[2], a[3]);
  o4[1] = make_float4(a[4], a[5], a[6], a[7]);
}

// ====== grouped GEMM, r12 core (verified 961 TF): 128x128, BK=64, 4 waves ====
// T2 XOR swizzle both-sides (conflicts 0, r12 counters); 32 KB LDS; VGPR=64.
// Change vs r12: launch_bounds(256,5) -> 5 blocks/CU (160 KB LDS exactly).
// r13 lesson: occupancy dominates LDS-traffic reduction in this 2-phase
// structure, so push the block count, not the tile size.
#define MFMA16 __builtin_amdgcn_mfma_f32_16x16x32_f16
template <int MODE>
__global__ __launch_bounds__(256, 5) void gemm128(
    const _Float16* __restrict__ A, const _Float16* __restrict__ BtAll,
    _Float16* __restrict__ C, const float* __restrict__ biasAll,
    const int* __restrict__ rlist, const int2* __restrict__ ttab,
    const int* __restrict__ ntilesp, int N, int K) {
  const int ncol = gridDim.x;
  const int b = blockIdx.y * ncol + blockIdx.x;
  const int xcd = b & 7, idx = b >> 3;
  const int ti = xcd * (MT128 / 8) + idx / ncol;   // XCD-chunked tile index
  const int colt = idx % ncol;
  if (ti >= *ntilesp) return;          // uniform exit, before any barrier
  const int2 tt = ttab[ti];
  const int e = tt.x, grow0 = tt.y;
  const int col0 = colt * 128;

  __shared__ _Float16 sA[128 * 64];
  __shared__ _Float16 sB[128 * 64];
  const int t = threadIdx.x;
  const int w = t >> 6, lane = t & 63;
  const int wm = w >> 1, wn = w & 1;
  const int l15 = lane & 15, lg = lane >> 4;

  const _Float16* Bt = BtAll + (size_t)e * N * K;

  // swizzled source column granule: row&7 == (t>>3)&7
  const int cb = (((t & 7) ^ ((t >> 3) & 7))) * 8;   // f16 units
  size_t arow[4], brow[4];
#pragma unroll
  for (int i = 0; i < 4; ++i) {
    const int chunk = i * 256 + t;
    const int r = chunk >> 3;               // 0..127 within tile
    const int gr = (MODE == 0) ? rlist[grow0 + r] : (grow0 + r);
    arow[i] = (size_t)gr * K;
    brow[i] = (size_t)(col0 + r) * K;
  }

  // fragment-read swizzled column offsets (f16 units); frag row&7 == l15&7
  const int ck0 = ((lg * 16) ^ ((l15 & 7) << 4)) >> 1;
  const int ck1 = ((64 + lg * 16) ^ ((l15 & 7) << 4)) >> 1;

  f32x4 acc[4][4] = {};

  for (int kt = 0; kt < K; kt += 64) {
    __syncthreads();
#pragma unroll
    for (int i = 0; i < 4; ++i)
      gload_lds16(A + arow[i] + kt + cb, sA + (i * 256 + w * 64) * 8);
#pragma unroll
    for (int i = 0; i < 4; ++i)
      gload_lds16(Bt + brow[i] + kt + cb, sB + (i * 256 + w * 64) * 8);
    __syncthreads();
#pragma unroll
    for (int k2 = 0; k2 < 2; ++k2) {
      const int ck = k2 ? ck1 : ck0;
      f16x8 af[4], bf[4];
#pragma unroll
      for (int m = 0; m < 4; ++m)
        af[m] = *(const f16x8*)(sA + (wm * 64 + m * 16 + l15) * 64 + ck);
#pragma unroll
      for (int n = 0; n < 4; ++n)
        bf[n] = *(const f16x8*)(sB + (wn * 64 + n * 16 + l15) * 64 + ck);
#pragma unroll
      for (int m = 0; m < 4; ++m)
#pragma unroll
        for (int n = 0; n < 4; ++n)
          acc[m][n] = MFMA16(af[m], bf[n], acc[m][n], 0, 0, 0);
    }
  }

  const float* bias = biasAll + (size_t)e * N;
#pragma unroll
  for (int m = 0; m < 4; ++m) {
#pragma unroll
    for (int n = 0; n < 4; ++n) {
      const int gc = col0 + wn * 64 + n * 16 + l15;
      const float bv = bias[gc];
#pragma unroll
      for (int r = 0; r < 4; ++r) {
        const int grow = grow0 + wm * 64 + m * 16 + lg * 4 + r;
        const float v = acc[m][n][r] + bv;
        C[(size_t)grow * N + gc] = (_Float16)((MODE == 2) ? v : fmaxf(v, 0.f));
      }
    }
  }
}

// ============ fallback (ws too small): per-expert path ============
__global__ void compact_old(const float* __restrict__ wg, int* __restrict__ cnt,
                            int* __restrict__ rowlist) {
  const int row = blockIdx.x * 256 + threadIdx.x;
  const int lane = threadIdx.x & 63;
#pragma unroll
  for (int e = 0; e < NEXP; ++e) {
    const float w = wg[(size_t)row * 8 + e];
    const bool keep = (w > 0.f);
    unsigned long long m = __ballot(keep);
    if (m) {
      const int leader = __ffsll(m) - 1;
      const int pre = __popcll(m & ((1ull << lane) - 1ull));
      int base = 0;
      if (lane == leader) base = atomicAdd(&cnt[e], __popcll(m));
      base = __shfl(base, leader);
      if (keep) rowlist[e * N_ROWS + base + pre] = row;
    }
  }
}

template <int MODE>  // 0: gather relu; 1: dense relu; 3: atomic out
__global__ __launch_bounds__(256, 2) void gemm_nt(
    const _Float16* __restrict__ A, const _Float16* __restrict__ Bt,
    void* __restrict__ Cout, const float* __restrict__ bias,
    const float* __restrict__ wg, const int* __restrict__ rlist,
    const int* __restrict__ cntp, int e, int N, int K) {
  const int M = *cntp;
  const int row0 = blockIdx.y * 128, col0 = blockIdx.x * 128;
  if (row0 >= M) return;
  __shared__ _Float16 sA[128 * 64];
  __shared__ _Float16 sB[128 * 64];
  const int t = threadIdx.x;
  const int w = t >> 6, lane = t & 63;
  const int wm = w >> 1, wn = w & 1;
  const int l15 = lane & 15, lg = lane >> 4;
  size_t arow[4];
#pragma unroll
  for (int i = 0; i < 4; ++i) {
    const int chunk = i * 256 + t;
    int li = row0 + (chunk >> 3);
    if (li >= M && MODE == 0) li = M - 1;
    const int gr = (MODE == 0) ? rlist[li] : li;
    arow[i] = (size_t)gr * K;
  }
  f32x4 acc[4][4] = {};
  for (int kt = 0; kt < K; kt += 64) {
    __syncthreads();
#pragma unroll
    for (int i = 0; i < 4; ++i) {
      const int chunk = i * 256 + t;
      const int cb = (chunk & 7) * 8;
      gload_lds16(A + arow[i] + kt + cb, sA + (i * 256 + w * 64) * 8);
    }
#pragma unroll
    for (int i = 0; i < 4; ++i) {
      const int chunk = i * 256 + t;
      const int r = chunk >> 3, cb = (chunk & 7) * 8;
      gload_lds16(Bt + (size_t)(col0 + r) * K + kt + cb, sB + (i * 256 + w * 64) * 8);
    }
    __syncthreads();
#pragma unroll
    for (int k2 = 0; k2 < 2; ++k2) {
      f16x8 af[4], bf[4];
#pragma unroll
      for (int m = 0; m < 4; ++m)
        af[m] = *(const f16x8*)(sA + (wm * 64 + m * 16 + l15) * 64 + k2 * 32 + lg * 8);
#pragma unroll
      for (int n = 0; n < 4; ++n)
        bf[n] = *(const f16x8*)(sB + (wn * 64 + n * 16 + l15) * 64 + k2 * 32 + lg * 8);
#pragma unroll
      for (int m = 0; m < 4; ++m)
#pragma unroll
        for (int n = 0; n < 4; ++n)
          acc[m][n] = MFMA16(af[m], bf[n], acc[m][n], 0, 0, 0);
    }
  }
#pragma unroll
  for (int m = 0; m < 4; ++m) {
#pragma unroll
    for (int n = 0; n < 4; ++n) {
      const int gc = col0 + wn * 64 + n * 16 + l15;
      const float bvv = bias[gc];
#pragma unroll
      for (int r = 0; r < 4; ++r) {
        const int gr = row0 + wm * 64 + m * 16 + lg * 4 + r;
        float v = acc[m][n][r] + bvv;
        if (MODE == 3) {
          if (gr < M) {
            const int orow = rlist[gr];
            atomicAdd((float*)Cout + (size_t)orow * N + gc,
                      wg[(size_t)orow * 8 + e] * v);
          }
        } else {
          ((_Float16*)Cout)[(size_t)gr * N + gc] = (_Float16)fmaxf(v, 0.f);
        }
      }
    }
  }
}

extern "C" void kernel_launch(void* const* d_in, const int* in_sizes, int n_in,
                              void* d_out, int out_size, void* d_ws, size_t ws_size,
                              hipStream_t stream) {
  const float* x  = (const float*)d_in[0];
  const float* gW = (const float*)d_in[1];
  const float* gb = (const float*)d_in[2];
  const float* W1 = (const float*)d_in[3];
  const float* b1 = (const float*)d_in[4];
  const float* W2 = (const float*)d_in[5];
  const float* b2 = (const float*)d_in[6];
  const float* W3 = (const float*)d_in[7];
  const float* b3 = (const float*)d_in[8];
  float* out = (float*)d_out;

  char* ws = (char*)d_ws;
  const bool big = (ws_size >= 0x1E100000ULL);   // 481 MiB needed for grouped path

  if (big) {
    float* wgate   = (float*)ws;                       // 256 KB
    int*   meta    = (int*)(ws + 0x40000);
    int*   cnt     = meta;
    int*   cursor  = meta + 8;
    int*   offs    = meta + 16;
    int*   ntiles  = meta + 24;
    int2*  ttab    = (int2*)(meta + 32);               // <=336 entries
    int*   pos     = (int*)(ws + 0x80000);             // [8192][8]
    int*   rlistg  = (int*)(ws + 0xC0000);             // <=41976 ints
    _Float16* xh   = (_Float16*)(ws + 0x100000);       // 16 MB
    _Float16* h1   = (_Float16*)(ws + 0x1100000);      // 168 MB
    _Float16* h2   = (_Float16*)(ws + 0xB900000);      // 168 MB
    _Float16* wt1  = (_Float16*)(ws + 0x16100000);     // 32 MB
    _Float16* wt2  = (_Float16*)(ws + 0x18100000);     // 64 MB
    _Float16* wt3  = (_Float16*)(ws + 0x1C100000);     // 32 MB
    _Float16* y    = h1;                               // reuse

    convert_x_kernel<<<(N_ROWS * DIM_D) / (256 * 8), 256, 0, stream>>>(x, xh, N_ROWS * DIM_D);
    gate_kernel<<<N_ROWS / 4, 256, 0, stream>>>(x, gW, gb, wgate);
    zero_counts_kernel<<<1, 64, 0, stream>>>(cnt);
    count_kernel<<<N_ROWS / 256, 256, 0, stream>>>(wgate, cnt);
    offsets_kernel<<<1, 256, 0, stream>>>(cnt, cursor, offs, ntiles, ttab, rlistg);
    place_kernel<<<N_ROWS / 256, 256, 0, stream>>>(wgate, offs, cursor, rlistg, pos);

    transpose_to_f16<<<dim3(DIM_H / 32, DIM_D / 32, NEXP), 256, 0, stream>>>(W1, wt1, DIM_D, DIM_H);
    transpose_to_f16<<<dim3(DIM_H / 32, DIM_H / 32, NEXP), 256, 0, stream>>>(W2, wt2, DIM_H, DIM_H);
    transpose_to_f16<<<dim3(DIM_O / 32, DIM_H / 32, NEXP), 256, 0, stream>>>(W3, wt3, DIM_H, DIM_O);

    gemm128<0><<<dim3(DIM_H / 128, MT128), 256, 0, stream>>>(
        xh, wt1, h1, b1, rlistg, ttab, ntiles, DIM_H, DIM_D);
    gemm128<1><<<dim3(DIM_H / 128, MT128), 256, 0, stream>>>(
        h1, wt2, h2, b2, rlistg, ttab, ntiles, DIM_H, DIM_H);
    gemm128<2><<<dim3(DIM_O / 128, MT128), 256, 0, stream>>>(
        h2, wt3, y, b3, rlistg, ttab, ntiles, DIM_O, DIM_H);

    combine_kernel<<<(N_ROWS * 128) / 256, 256, 0, stream>>>(wgate, pos, y, out);
  } else {
    // fallback: per-expert path with atomic final accumulate
    float*    wgate = (float*)ws;
    int*      cnt   = (int*)(ws + 0x40000);
    int*      rlist = (int*)(ws + 0x80000);
    _Float16* xh    = (_Float16*)(ws + 0x100000);
    _Float16* h1    = (_Float16*)(ws + 0x1100000);
    _Float16* h2    = (_Float16*)(ws + 0x3100000);
    _Float16* wt1   = (_Float16*)(ws + 0x5100000);
    _Float16* wt2   = (_Float16*)(ws + 0x5500000);
    _Float16* wt3   = (_Float16*)(ws + 0x5D00000);

    convert_x_kernel<<<(N_ROWS * DIM_D) / (256 * 8), 256, 0, stream>>>(x, xh, N_ROWS * DIM_D);
    gate_kernel<<<N_ROWS / 4, 256, 0, stream>>>(x, gW, gb, wgate);
    zero_counts_kernel<<<1, 64, 0, stream>>>(cnt);
    compact_old<<<N_ROWS / 256, 256, 0, stream>>>(wgate, cnt, rlist);
    zero_f32_kernel<<<(N_ROWS * DIM_O / 4 + 255) / 256, 256, 0, stream>>>(out, N_ROWS * DIM_O / 4);

    for (int e = 0; e < NEXP; ++e) {
      transpose_to_f16<<<dim3(DIM_H / 32, DIM_D / 32), 256, 0, stream>>>(
          W1 + (size_t)e * DIM_D * DIM_H, wt1, DIM_D, DIM_H);
      transpose_to_f16<<<dim3(DIM_H / 32, DIM_H / 32), 256, 0, stream>>>(
          W2 + (size_t)e * DIM_H * DIM_H, wt2, DIM_H, DIM_H);
      transpose_to_f16<<<dim3(DIM_O / 32, DIM_H / 32), 256, 0, stream>>>(
          W3 + (size_t)e * DIM_H * DIM_O, wt3, DIM_H, DIM_O);
      const int* ce = cnt + e;
      const int* re = rlist + e * N_ROWS;
      gemm_nt<0><<<dim3(DIM_H / 128, N_ROWS / 128), 256, 0, stream>>>(
          xh, wt1, h1, b1 + (size_t)e * DIM_H, wgate, re, ce, e, DIM_H, DIM_D);
      gemm_nt<1><<<dim3(DIM_H / 128, N_ROWS / 128), 256, 0, stream>>>(
          h1, wt2, h2, b2 + (size_t)e * DIM_H, wgate, re, ce, e, DIM_H, DIM_H);
      gemm_nt<3><<<dim3(DIM_O / 128, N_ROWS / 128), 256, 0, stream>>>(
          h2, wt3, out, b3 + (size_t)e * DIM_O, wgate, re, ce, e, DIM_O, DIM_H);
    }
  }
}

// Round 15
// 887.525 us; speedup vs baseline: 2.5339x; 2.5339x over previous
//
#include <hip/hip_runtime.h>

#define N_ROWS 8192
#define DIM_D  1024
#define DIM_H  2048
#define DIM_O  1024
#define NEXP   8
#define NACT   5
#define MT128  336   // max 128-row tiles (8 * 42)

typedef _Float16 f16x8 __attribute__((ext_vector_type(8)));
typedef _Float16 f16x4 __attribute__((ext_vector_type(4)));
typedef float    f32x4 __attribute__((ext_vector_type(4)));

__device__ __forceinline__ void gload_lds16(const void* g, void* l) {
  __builtin_amdgcn_global_load_lds(
      (const __attribute__((address_space(1))) void*)g,
      (__attribute__((address_space(3))) void*)l, 16, 0, 0);
}

// ---------------- x: f32 -> f16 ----------------
__global__ void convert_x_kernel(const float* __restrict__ in,
                                 _Float16* __restrict__ out, int n) {
  int i = (blockIdx.x * 256 + threadIdx.x) * 8;
  if (i >= n) return;
  const float4 a = *(const float4*)(in + i);
  const float4 b = *(const float4*)(in + i + 4);
  f16x8 v;
  v[0] = (_Float16)a.x; v[1] = (_Float16)a.y; v[2] = (_Float16)a.z; v[3] = (_Float16)a.w;
  v[4] = (_Float16)b.x; v[5] = (_Float16)b.y; v[6] = (_Float16)b.z; v[7] = (_Float16)b.w;
  *(f16x8*)(out + i) = v;
}

// ---------------- zero helpers ----------------
__global__ void zero_f32_kernel(float* __restrict__ p, int n4) {
  int i = blockIdx.x * 256 + threadIdx.x;
  if (i < n4) ((float4*)p)[i] = make_float4(0.f, 0.f, 0.f, 0.f);
}
__global__ void zero_counts_kernel(int* __restrict__ cnt) {
  if (threadIdx.x < NEXP) cnt[threadIdx.x] = 0;
}

// ------- W [R][C] f32 -> Wt [C][R] f16 (batched over z), vectorized writes ---
__global__ void transpose_to_f16(const float* __restrict__ in,
                                 _Float16* __restrict__ out, int R, int C) {
  in  += (size_t)blockIdx.z * R * C;
  out += (size_t)blockIdx.z * R * C;
  __shared__ float tile[32][33];
  const int tx = threadIdx.x & 31, ty = threadIdx.x >> 5;  // ty: 0..7
  const int c0 = blockIdx.x * 32, r0 = blockIdx.y * 32;
#pragma unroll
  for (int j = 0; j < 32; j += 8)
    tile[ty + j][tx] = in[(size_t)(r0 + ty + j) * C + c0 + tx];
  __syncthreads();
  const int cc = threadIdx.x >> 3;        // 0..31
  const int r4 = (threadIdx.x & 7) * 4;   // 0..28
  f16x4 v;
#pragma unroll
  for (int i = 0; i < 4; ++i) v[i] = (_Float16)tile[r4 + i][cc];
  *(f16x4*)(out + (size_t)(c0 + cc) * R + r0 + r4) = v;
}

// ---------------- gate: softmax(score/e), top-5, renorm ----------------
__global__ void gate_kernel(const float* __restrict__ x, const float* __restrict__ gW,
                            const float* __restrict__ gb, float* __restrict__ wout) {
  const int lane = threadIdx.x & 63;
  const int row  = blockIdx.x * 4 + (threadIdx.x >> 6);
  float acc[8] = {0.f,0.f,0.f,0.f,0.f,0.f,0.f,0.f};
  const float* xr = x + (size_t)row * DIM_D;
  for (int d = lane; d < DIM_D; d += 64) {
    float xv = xr[d];
    const float4* g4 = (const float4*)(gW + d * 8);
    float4 a = g4[0], b = g4[1];
    acc[0] += xv * a.x; acc[1] += xv * a.y; acc[2] += xv * a.z; acc[3] += xv * a.w;
    acc[4] += xv * b.x; acc[5] += xv * b.y; acc[6] += xv * b.z; acc[7] += xv * b.w;
  }
#pragma unroll
  for (int off = 32; off > 0; off >>= 1) {
#pragma unroll
    for (int e = 0; e < 8; ++e) acc[e] += __shfl_xor(acc[e], off);
  }
  const float invT = 0.36787944117144233f;  // 1/e
  float s[8], mx = -1e30f;
#pragma unroll
  for (int e = 0; e < 8; ++e) { s[e] = (acc[e] + gb[e]) * invT; mx = fmaxf(mx, s[e]); }
  float p[8], sum = 0.f;
#pragma unroll
  for (int e = 0; e < 8; ++e) { p[e] = expf(s[e] - mx); sum += p[e]; }
  float inv = 1.f / sum;
#pragma unroll
  for (int e = 0; e < 8; ++e) p[e] *= inv;
  unsigned keep = 0;
  for (int it = 0; it < NACT; ++it) {
    int best = 0; float bv = -1.f;
#pragma unroll
    for (int e = 0; e < 8; ++e)
      if (!(keep & (1u << e)) && p[e] > bv) { bv = p[e]; best = e; }
    keep |= 1u << best;
  }
  float ks = 0.f;
#pragma unroll
  for (int e = 0; e < 8; ++e) if (keep & (1u << e)) ks += p[e];
  const float winv = 1.f / (ks + 1e-8f);
  if (lane < 8)
    wout[(size_t)row * 8 + lane] = (keep & (1u << lane)) ? p[lane] * winv : 0.f;
}

// ---------------- count kept rows per expert ----------------
__global__ void count_kernel(const float* __restrict__ wg, int* __restrict__ cnt) {
  const int row = blockIdx.x * 256 + threadIdx.x;
  const int lane = threadIdx.x & 63;
#pragma unroll
  for (int e = 0; e < NEXP; ++e) {
    const bool keep = wg[(size_t)row * 8 + e] > 0.f;
    unsigned long long m = __ballot(keep);
    if (lane == 0 && m) atomicAdd(&cnt[e], __popcll(m));
  }
}

// ---------------- padded offsets (128-granular) + tile table + pad-fill ------
__global__ void offsets_kernel(const int* __restrict__ cnt, int* __restrict__ cursor,
                               int* __restrict__ offs, int* __restrict__ ntiles,
                               int2* __restrict__ ttab, int* __restrict__ rlist) {
  __shared__ int soffs[NEXP], scnt[NEXP];
  if (threadIdx.x == 0) {
    int off = 0, k = 0;
    for (int e = 0; e < NEXP; ++e) {
      offs[e] = off; soffs[e] = off; scnt[e] = cnt[e];
      cursor[e] = 0;
      const int nt = (cnt[e] + 127) >> 7;
      for (int t2 = 0; t2 < nt; ++t2) { ttab[k] = make_int2(e, off + t2 * 128); ++k; }
      off += nt << 7;
    }
    *ntiles = k;
  }
  __syncthreads();
#pragma unroll
  for (int e = 0; e < NEXP; ++e) {
    const int lo = soffs[e] + scnt[e];
    const int hi = soffs[e] + ((scnt[e] + 127) & ~127);
    for (int i = lo + (int)threadIdx.x; i < hi; i += 256) rlist[i] = 0;
  }
}

// ---------------- place rows into padded compact space ----------------
__global__ void place_kernel(const float* __restrict__ wg, const int* __restrict__ offs,
                             int* __restrict__ cursor, int* __restrict__ rlist,
                             int* __restrict__ pos) {
  const int row = blockIdx.x * 256 + threadIdx.x;
  const int lane = threadIdx.x & 63;
#pragma unroll
  for (int e = 0; e < NEXP; ++e) {
    const bool keep = wg[(size_t)row * 8 + e] > 0.f;
    unsigned long long m = __ballot(keep);
    if (m) {
      const int leader = __ffsll(m) - 1;
      const int pre = __popcll(m & ((1ull << lane) - 1ull));
      int base = 0;
      if (lane == leader) base = atomicAdd(&cursor[e], __popcll(m));
      base = __shfl(base, leader);
      if (keep) {
        const int idx = offs[e] + base + pre;
        rlist[idx] = row;
        pos[(size_t)row * 8 + e] = idx;
      }
    }
  }
}

// ---------------- combine: out[row] = sum_e w * y[pos[row][e]] ----------------
__global__ void combine_kernel(const float* __restrict__ wg, const int* __restrict__ pos,
                               const _Float16* __restrict__ y, float* __restrict__ out) {
  const int tid = blockIdx.x * 256 + threadIdx.x;
  const int row = tid >> 7, c8 = (tid & 127) * 8;
  float a[8] = {0.f,0.f,0.f,0.f,0.f,0.f,0.f,0.f};
#pragma unroll
  for (int e = 0; e < NEXP; ++e) {
    const float w = wg[(size_t)row * 8 + e];
    if (w > 0.f) {
      const int p = pos[(size_t)row * 8 + e];
      const f16x8 v = *(const f16x8*)(y + (size_t)p * DIM_O + c8);
#pragma unroll
      for (int j = 0; j < 8; ++j) a[j] += w * (float)v[j];
    }
  }
  float4* o4 = (float4*)(out + (size_t)row * DIM_O + c8);
  o4[0] = make_float4(a[0], a[1], a[2], a[3]);
  o4[1] = make_float4(a[4], a[5], a[6], a[7]);
}

// ====== grouped GEMM, r12 core verbatim: 128x128, BK=64, 4 waves, (256,4) ====
// r14 lesson: launch_bounds(256,5) forces VGPR<=48 -> acc spills to scratch
// (WRITE_SIZE 166MB -> 2.1GB, MfmaUtil 13%). (256,4)/VGPR=64 is the verified
// local optimum: 4 blocks/CU, conflicts 0, 961 TF (r12 counters).
#define MFMA16 __builtin_amdgcn_mfma_f32_16x16x32_f16
template <int MODE>
__global__ __launch_bounds__(256, 4) void gemm128(
    const _Float16* __restrict__ A, const _Float16* __restrict__ BtAll,
    _Float16* __restrict__ C, const float* __restrict__ biasAll,
    const int* __restrict__ rlist, const int2* __restrict__ ttab,
    const int* __restrict__ ntilesp, int N, int K) {
  const int ncol = gridDim.x;
  const int b = blockIdx.y * ncol + blockIdx.x;
  const int xcd = b & 7, idx = b >> 3;
  const int ti = xcd * (MT128 / 8) + idx / ncol;   // XCD-chunked tile index
  const int colt = idx % ncol;
  if (ti >= *ntilesp) return;          // uniform exit, before any barrier
  const int2 tt = ttab[ti];
  const int e = tt.x, grow0 = tt.y;
  const int col0 = colt * 128;

  __shared__ _Float16 sA[128 * 64];
  __shared__ _Float16 sB[128 * 64];
  const int t = threadIdx.x;
  const int w = t >> 6, lane = t & 63;
  const int wm = w >> 1, wn = w & 1;
  const int l15 = lane & 15, lg = lane >> 4;

  const _Float16* Bt = BtAll + (size_t)e * N * K;

  // swizzled source column granule: row&7 == (t>>3)&7
  const int cb = (((t & 7) ^ ((t >> 3) & 7))) * 8;   // f16 units
  size_t arow[4], brow[4];
#pragma unroll
  for (int i = 0; i < 4; ++i) {
    const int chunk = i * 256 + t;
    const int r = chunk >> 3;               // 0..127 within tile
    const int gr = (MODE == 0) ? rlist[grow0 + r] : (grow0 + r);
    arow[i] = (size_t)gr * K;
    brow[i] = (size_t)(col0 + r) * K;
  }

  // fragment-read swizzled column offsets (f16 units); frag row&7 == l15&7
  const int ck0 = ((lg * 16) ^ ((l15 & 7) << 4)) >> 1;
  const int ck1 = ((64 + lg * 16) ^ ((l15 & 7) << 4)) >> 1;

  f32x4 acc[4][4] = {};

  for (int kt = 0; kt < K; kt += 64) {
    __syncthreads();
#pragma unroll
    for (int i = 0; i < 4; ++i)
      gload_lds16(A + arow[i] + kt + cb, sA + (i * 256 + w * 64) * 8);
#pragma unroll
    for (int i = 0; i < 4; ++i)
      gload_lds16(Bt + brow[i] + kt + cb, sB + (i * 256 + w * 64) * 8);
    __syncthreads();
#pragma unroll
    for (int k2 = 0; k2 < 2; ++k2) {
      const int ck = k2 ? ck1 : ck0;
      f16x8 af[4], bf[4];
#pragma unroll
      for (int m = 0; m < 4; ++m)
        af[m] = *(const f16x8*)(sA + (wm * 64 + m * 16 + l15) * 64 + ck);
#pragma unroll
      for (int n = 0; n < 4; ++n)
        bf[n] = *(const f16x8*)(sB + (wn * 64 + n * 16 + l15) * 64 + ck);
#pragma unroll
      for (int m = 0; m < 4; ++m)
#pragma unroll
        for (int n = 0; n < 4; ++n)
          acc[m][n] = MFMA16(af[m], bf[n], acc[m][n], 0, 0, 0);
    }
  }

  const float* bias = biasAll + (size_t)e * N;
#pragma unroll
  for (int m = 0; m < 4; ++m) {
#pragma unroll
    for (int n = 0; n < 4; ++n) {
      const int gc = col0 + wn * 64 + n * 16 + l15;
      const float bv = bias[gc];
#pragma unroll
      for (int r = 0; r < 4; ++r) {
        const int grow = grow0 + wm * 64 + m * 16 + lg * 4 + r;
        const float v = acc[m][n][r] + bv;
        C[(size_t)grow * N + gc] = (_Float16)((MODE == 2) ? v : fmaxf(v, 0.f));
      }
    }
  }
}

// ============ fallback (ws too small): per-expert path ============
__global__ void compact_old(const float* __restrict__ wg, int* __restrict__ cnt,
                            int* __restrict__ rowlist) {
  const int row = blockIdx.x * 256 + threadIdx.x;
  const int lane = threadIdx.x & 63;
#pragma unroll
  for (int e = 0; e < NEXP; ++e) {
    const float w = wg[(size_t)row * 8 + e];
    const bool keep = (w > 0.f);
    unsigned long long m = __ballot(keep);
    if (m) {
      const int leader = __ffsll(m) - 1;
      const int pre = __popcll(m & ((1ull << lane) - 1ull));
      int base = 0;
      if (lane == leader) base = atomicAdd(&cnt[e], __popcll(m));
      base = __shfl(base, leader);
      if (keep) rowlist[e * N_ROWS + base + pre] = row;
    }
  }
}

template <int MODE>  // 0: gather relu; 1: dense relu; 3: atomic out
__global__ __launch_bounds__(256, 2) void gemm_nt(
    const _Float16* __restrict__ A, const _Float16* __restrict__ Bt,
    void* __restrict__ Cout, const float* __restrict__ bias,
    const float* __restrict__ wg, const int* __restrict__ rlist,
    const int* __restrict__ cntp, int e, int N, int K) {
  const int M = *cntp;
  const int row0 = blockIdx.y * 128, col0 = blockIdx.x * 128;
  if (row0 >= M) return;
  __shared__ _Float16 sA[128 * 64];
  __shared__ _Float16 sB[128 * 64];
  const int t = threadIdx.x;
  const int w = t >> 6, lane = t & 63;
  const int wm = w >> 1, wn = w & 1;
  const int l15 = lane & 15, lg = lane >> 4;
  size_t arow[4];
#pragma unroll
  for (int i = 0; i < 4; ++i) {
    const int chunk = i * 256 + t;
    int li = row0 + (chunk >> 3);
    if (li >= M && MODE == 0) li = M - 1;
    const int gr = (MODE == 0) ? rlist[li] : li;
    arow[i] = (size_t)gr * K;
  }
  f32x4 acc[4][4] = {};
  for (int kt = 0; kt < K; kt += 64) {
    __syncthreads();
#pragma unroll
    for (int i = 0; i < 4; ++i) {
      const int chunk = i * 256 + t;
      const int cb = (chunk & 7) * 8;
      gload_lds16(A + arow[i] + kt + cb, sA + (i * 256 + w * 64) * 8);
    }
#pragma unroll
    for (int i = 0; i < 4; ++i) {
      const int chunk = i * 256 + t;
      const int r = chunk >> 3, cb = (chunk & 7) * 8;
      gload_lds16(Bt + (size_t)(col0 + r) * K + kt + cb, sB + (i * 256 + w * 64) * 8);
    }
    __syncthreads();
#pragma unroll
    for (int k2 = 0; k2 < 2; ++k2) {
      f16x8 af[4], bf[4];
#pragma unroll
      for (int m = 0; m < 4; ++m)
        af[m] = *(const f16x8*)(sA + (wm * 64 + m * 16 + l15) * 64 + k2 * 32 + lg * 8);
#pragma unroll
      for (int n = 0; n < 4; ++n)
        bf[n] = *(const f16x8*)(sB + (wn * 64 + n * 16 + l15) * 64 + k2 * 32 + lg * 8);
#pragma unroll
      for (int m = 0; m < 4; ++m)
#pragma unroll
        for (int n = 0; n < 4; ++n)
          acc[m][n] = MFMA16(af[m], bf[n], acc[m][n], 0, 0, 0);
    }
  }
#pragma unroll
  for (int m = 0; m < 4; ++m) {
#pragma unroll
    for (int n = 0; n < 4; ++n) {
      const int gc = col0 + wn * 64 + n * 16 + l15;
      const float bvv = bias[gc];
#pragma unroll
      for (int r = 0; r < 4; ++r) {
        const int gr = row0 + wm * 64 + m * 16 + lg * 4 + r;
        float v = acc[m][n][r] + bvv;
        if (MODE == 3) {
          if (gr < M) {
            const int orow = rlist[gr];
            atomicAdd((float*)Cout + (size_t)orow * N + gc,
                      wg[(size_t)orow * 8 + e] * v);
          }
        } else {
          ((_Float16*)Cout)[(size_t)gr * N + gc] = (_Float16)fmaxf(v, 0.f);
        }
      }
    }
  }
}

extern "C" void kernel_launch(void* const* d_in, const int* in_sizes, int n_in,
                              void* d_out, int out_size, void* d_ws, size_t ws_size,
                              hipStream_t stream) {
  const float* x  = (const float*)d_in[0];
  const float* gW = (const float*)d_in[1];
  const float* gb = (const float*)d_in[2];
  const float* W1 = (const float*)d_in[3];
  const float* b1 = (const float*)d_in[4];
  const float* W2 = (const float*)d_in[5];
  const float* b2 = (const float*)d_in[6];
  const float* W3 = (const float*)d_in[7];
  const float* b3 = (const float*)d_in[8];
  float* out = (float*)d_out;

  char* ws = (char*)d_ws;
  const bool big = (ws_size >= 0x1E100000ULL);   // 481 MiB needed for grouped path

  if (big) {
    float* wgate   = (float*)ws;                       // 256 KB
    int*   meta    = (int*)(ws + 0x40000);
    int*   cnt     = meta;
    int*   cursor  = meta + 8;
    int*   offs    = meta + 16;
    int*   ntiles  = meta + 24;
    int2*  ttab    = (int2*)(meta + 32);               // <=336 entries
    int*   pos     = (int*)(ws + 0x80000);             // [8192][8]
    int*   rlistg  = (int*)(ws + 0xC0000);             // <=41976 ints
    _Float16* xh   = (_Float16*)(ws + 0x100000);       // 16 MB
    _Float16* h1   = (_Float16*)(ws + 0x1100000);      // 168 MB
    _Float16* h2   = (_Float16*)(ws + 0xB900000);      // 168 MB
    _Float16* wt1  = (_Float16*)(ws + 0x16100000);     // 32 MB
    _Float16* wt2  = (_Float16*)(ws + 0x18100000);     // 64 MB
    _Float16* wt3  = (_Float16*)(ws + 0x1C100000);     // 32 MB
    _Float16* y    = h1;                               // reuse

    convert_x_kernel<<<(N_ROWS * DIM_D) / (256 * 8), 256, 0, stream>>>(x, xh, N_ROWS * DIM_D);
    gate_kernel<<<N_ROWS / 4, 256, 0, stream>>>(x, gW, gb, wgate);
    zero_counts_kernel<<<1, 64, 0, stream>>>(cnt);
    count_kernel<<<N_ROWS / 256, 256, 0, stream>>>(wgate, cnt);
    offsets_kernel<<<1, 256, 0, stream>>>(cnt, cursor, offs, ntiles, ttab, rlistg);
    place_kernel<<<N_ROWS / 256, 256, 0, stream>>>(wgate, offs, cursor, rlistg, pos);

    transpose_to_f16<<<dim3(DIM_H / 32, DIM_D / 32, NEXP), 256, 0, stream>>>(W1, wt1, DIM_D, DIM_H);
    transpose_to_f16<<<dim3(DIM_H / 32, DIM_H / 32, NEXP), 256, 0, stream>>>(W2, wt2, DIM_H, DIM_H);
    transpose_to_f16<<<dim3(DIM_O / 32, DIM_H / 32, NEXP), 256, 0, stream>>>(W3, wt3, DIM_H, DIM_O);

    gemm128<0><<<dim3(DIM_H / 128, MT128), 256, 0, stream>>>(
        xh, wt1, h1, b1, rlistg, ttab, ntiles, DIM_H, DIM_D);
    gemm128<1><<<dim3(DIM_H / 128, MT128), 256, 0, stream>>>(
        h1, wt2, h2, b2, rlistg, ttab, ntiles, DIM_H, DIM_H);
    gemm128<2><<<dim3(DIM_O / 128, MT128), 256, 0, stream>>>(
        h2, wt3, y, b3, rlistg, ttab, ntiles, DIM_O, DIM_H);

    combine_kernel<<<(N_ROWS * 128) / 256, 256, 0, stream>>>(wgate, pos, y, out);
  } else {
    // fallback: per-expert path with atomic final accumulate
    float*    wgate = (float*)ws;
    int*      cnt   = (int*)(ws + 0x40000);
    int*      rlist = (int*)(ws + 0x80000);
    _Float16* xh    = (_Float16*)(ws + 0x100000);
    _Float16* h1    = (_Float16*)(ws + 0x1100000);
    _Float16* h2    = (_Float16*)(ws + 0x3100000);
    _Float16* wt1   = (_Float16*)(ws + 0x5100000);
    _Float16* wt2   = (_Float16*)(ws + 0x5500000);
    _Float16* wt3   = (_Float16*)(ws + 0x5D00000);

    convert_x_kernel<<<(N_ROWS * DIM_D) / (256 * 8), 256, 0, stream>>>(x, xh, N_ROWS * DIM_D);
    gate_kernel<<<N_ROWS / 4, 256, 0, stream>>>(x, gW, gb, wgate);
    zero_counts_kernel<<<1, 64, 0, stream>>>(cnt);
    compact_old<<<N_ROWS / 256, 256, 0, stream>>>(wgate, cnt, rlist);
    zero_f32_kernel<<<(N_ROWS * DIM_O / 4 + 255) / 256, 256, 0, stream>>>(out, N_ROWS * DIM_O / 4);

    for (int e = 0; e < NEXP; ++e) {
      transpose_to_f16<<<dim3(DIM_H / 32, DIM_D / 32, 1), 256, 0, stream>>>(
          W1 + (size_t)e * DIM_D * DIM_H, wt1, DIM_D, DIM_H);
      transpose_to_f16<<<dim3(DIM_H / 32, DIM_H / 32, 1), 256, 0, stream>>>(
          W2 + (size_t)e * DIM_H * DIM_H, wt2, DIM_H, DIM_H);
      transpose_to_f16<<<dim3(DIM_O / 32, DIM_H / 32, 1), 256, 0, stream>>>(
          W3 + (size_t)e * DIM_H * DIM_O, wt3, DIM_H, DIM_O);
      const int* ce = cnt + e;
      const int* re = rlist + e * N_ROWS;
      gemm_nt<0><<<dim3(DIM_H / 128, N_ROWS / 128), 256, 0, stream>>>(
          xh, wt1, h1, b1 + (size_t)e * DIM_H, wgate, re, ce, e, DIM_H, DIM_D);
      gemm_nt<1><<<dim3(DIM_H / 128, N_ROWS / 128), 256, 0, stream>>>(
          h1, wt2, h2, b2 + (size_t)e * DIM_H, wgate, re, ce, e, DIM_H, DIM_H);
      gemm_nt<3><<<dim3(DIM_O / 128, N_ROWS / 128), 256, 0, stream>>>(
          h2, wt3, out, b3 + (size_t)e * DIM_O, wgate, re, ce, e, DIM_O, DIM_H);
    }
  }
}